// Round 12
// baseline (230.680 us; speedup 1.0000x reference)
//
#include <hip/hip_runtime.h>

static constexpr int IN_F = 256;
static constexpr int OUT_F = 128;
static constexpr int BM = 64, BN = 128, BK = 32;
static constexpr int NT = IN_F / BK;  // 8 K-tiles

// ---------------------------------------------------------------------------
// Histogram (standalone, grid-stride): deg counts + per-edge slot into tmp.
// ---------------------------------------------------------------------------
__global__ __launch_bounds__(256) void hist_kernel(
    const int* __restrict__ dst, int* __restrict__ deg, int* __restrict__ tmp,
    int E) {
  const int stride = (int)gridDim.x * 256;
  for (int e = (int)blockIdx.x * 256 + (int)threadIdx.x; e < E; e += stride) {
    const int s = atomicAdd(&deg[dst[e]], 1);
    if (tmp) tmp[e] = s;
  }
}

// ---------------------------------------------------------------------------
// Single-block scan (proven in rounds 5/6): deg[n] -> exclusive off[n+1].
// ---------------------------------------------------------------------------
__global__ __launch_bounds__(1024) void scan_kernel(const int* __restrict__ deg,
                                                    int* __restrict__ off, int n) {
  __shared__ int partial[1024];
  const int tid = threadIdx.x;
  const int chunk = (n + 1023) / 1024;
  const int begin = tid * chunk;
  const int end = min(begin + chunk, n);
  int sum = 0;
  for (int i = begin; i < end; ++i) sum += deg[i];
  partial[tid] = sum;
  __syncthreads();
  for (int d = 1; d < 1024; d <<= 1) {
    int v = (tid >= d) ? partial[tid - d] : 0;
    __syncthreads();
    partial[tid] += v;
    __syncthreads();
  }
  int prefix = (tid == 0) ? 0 : partial[tid - 1];
  for (int i = begin; i < end; ++i) {
    off[i] = prefix;
    prefix += deg[i];
  }
  if (tid == 1023) off[n] = prefix;
}

// ---------------------------------------------------------------------------
// Fused: blocks [0, gemmBlocks) = round-9 GEMM verbatim (BM=64, BK=32, 4x8
// micro-tile, 256 threads, single LDS buffer + register prefetch, 71.5 us
// proven). Blocks >= gemmBlocks: grid-stride placement (NO atomics):
// pos = off[dst[e]] + tmp[e]; pay[pos] = (src, val).
// ---------------------------------------------------------------------------
__global__ __launch_bounds__(256) void gemm_place_kernel(
    const float* __restrict__ X, const float* __restrict__ W,
    const float* __restrict__ bias, float* __restrict__ H, int M,
    const int* __restrict__ dst, const int* __restrict__ src,
    const float* __restrict__ vals, const int* __restrict__ off,
    const int* __restrict__ tmp, int2* __restrict__ pay, int E,
    int gemmBlocks, int placeBlocks) {
  if ((int)blockIdx.x >= gemmBlocks) {
    if (pay) {
      const int stride = placeBlocks * 256;
      for (int e = ((int)blockIdx.x - gemmBlocks) * 256 + (int)threadIdx.x;
           e < E; e += stride) {
        const int pos = off[dst[e]] + tmp[e];
        pay[pos] = make_int2(src[e], __float_as_int(vals[e]));
      }
    }
    return;
  }

  __shared__ float As[BK][BM + 4];  // 32 x 68 x 4B = 8704 B
  __shared__ float Bs[BK][BN];      // 32 x 128 x 4B = 16384 B

  const int tid = threadIdx.x;
  const int tx = tid & 15;   // cols tx*4..+3 and 64+tx*4..+3
  const int ty = tid >> 4;   // rows ty*4..+3
  const int row0 = (int)blockIdx.x * BM;

  const int ar = tid >> 3;          // 0..31 (+32)
  const int ac4 = (tid & 7) << 2;   // 0,4,..,28
  const int bk_ = tid >> 5;         // 0..7
  const int bn4 = (tid & 31) << 2;  // 0..124

  float acc[4][8];
#pragma unroll
  for (int i = 0; i < 4; ++i)
#pragma unroll
    for (int j = 0; j < 8; ++j) acc[i][j] = 0.f;

  const float4 fz = make_float4(0.f, 0.f, 0.f, 0.f);
  const int gr0 = row0 + ar;
  const int gr1 = row0 + ar + 32;

  // Prologue: tile 0 -> registers.
  float4 cA0 = (gr0 < M) ? *(const float4*)(X + (size_t)gr0 * IN_F + ac4) : fz;
  float4 cA1 = (gr1 < M) ? *(const float4*)(X + (size_t)gr1 * IN_F + ac4) : fz;
  float4 cB0 = *(const float4*)(W + (size_t)(bk_ + 0) * OUT_F + bn4);
  float4 cB1 = *(const float4*)(W + (size_t)(bk_ + 8) * OUT_F + bn4);
  float4 cB2 = *(const float4*)(W + (size_t)(bk_ + 16) * OUT_F + bn4);
  float4 cB3 = *(const float4*)(W + (size_t)(bk_ + 24) * OUT_F + bn4);

#pragma unroll 1
  for (int t = 0; t < NT; ++t) {
    // Stage current tile regs -> LDS.
    As[ac4 + 0][ar] = cA0.x; As[ac4 + 1][ar] = cA0.y;
    As[ac4 + 2][ar] = cA0.z; As[ac4 + 3][ar] = cA0.w;
    As[ac4 + 0][ar + 32] = cA1.x; As[ac4 + 1][ar + 32] = cA1.y;
    As[ac4 + 2][ar + 32] = cA1.z; As[ac4 + 3][ar + 32] = cA1.w;
    *(float4*)&Bs[bk_ + 0][bn4] = cB0;
    *(float4*)&Bs[bk_ + 8][bn4] = cB1;
    *(float4*)&Bs[bk_ + 16][bn4] = cB2;
    *(float4*)&Bs[bk_ + 24][bn4] = cB3;
    __syncthreads();

    // Prefetch next tile (in flight through the compute phase).
    if (t + 1 < NT) {
      const int k0 = (t + 1) * BK;
      cA0 = (gr0 < M) ? *(const float4*)(X + (size_t)gr0 * IN_F + k0 + ac4) : fz;
      cA1 = (gr1 < M) ? *(const float4*)(X + (size_t)gr1 * IN_F + k0 + ac4) : fz;
      cB0 = *(const float4*)(W + (size_t)(k0 + bk_ + 0) * OUT_F + bn4);
      cB1 = *(const float4*)(W + (size_t)(k0 + bk_ + 8) * OUT_F + bn4);
      cB2 = *(const float4*)(W + (size_t)(k0 + bk_ + 16) * OUT_F + bn4);
      cB3 = *(const float4*)(W + (size_t)(k0 + bk_ + 24) * OUT_F + bn4);
    }

#pragma unroll
    for (int kk = 0; kk < BK; ++kk) {
      const float4 a = *(const float4*)&As[kk][ty * 4];
      const float4 b0 = *(const float4*)&Bs[kk][tx * 4];
      const float4 b1 = *(const float4*)&Bs[kk][64 + tx * 4];
      const float av[4] = {a.x, a.y, a.z, a.w};
#pragma unroll
      for (int i = 0; i < 4; ++i) {
        acc[i][0] = fmaf(av[i], b0.x, acc[i][0]);
        acc[i][1] = fmaf(av[i], b0.y, acc[i][1]);
        acc[i][2] = fmaf(av[i], b0.z, acc[i][2]);
        acc[i][3] = fmaf(av[i], b0.w, acc[i][3]);
        acc[i][4] = fmaf(av[i], b1.x, acc[i][4]);
        acc[i][5] = fmaf(av[i], b1.y, acc[i][5]);
        acc[i][6] = fmaf(av[i], b1.z, acc[i][6]);
        acc[i][7] = fmaf(av[i], b1.w, acc[i][7]);
      }
    }
    __syncthreads();
  }

  float bv0[4], bv1[4];
#pragma unroll
  for (int j = 0; j < 4; ++j) {
    bv0[j] = bias[tx * 4 + j];
    bv1[j] = bias[64 + tx * 4 + j];
  }
#pragma unroll
  for (int i = 0; i < 4; ++i) {
    const int gr = row0 + ty * 4 + i;
    if (gr < M) {
      float4 o0, o1;
      o0.x = acc[i][0] + bv0[0]; o0.y = acc[i][1] + bv0[1];
      o0.z = acc[i][2] + bv0[2]; o0.w = acc[i][3] + bv0[3];
      o1.x = acc[i][4] + bv1[0]; o1.y = acc[i][5] + bv1[1];
      o1.z = acc[i][6] + bv1[2]; o1.w = acc[i][7] + bv1[3];
      *(float4*)(H + (size_t)gr * OUT_F + tx * 4) = o0;
      *(float4*)(H + (size_t)gr * OUT_F + 64 + tx * 4) = o1;
    }
  }
}

// ---------------------------------------------------------------------------
// Fallback scan machinery (tiers 1/2 only): 3-kernel scan producing cursor.
// ---------------------------------------------------------------------------
__global__ __launch_bounds__(256) void scan_partial_kernel(
    const int* __restrict__ deg, int* __restrict__ bsum, int n) {
  __shared__ int red[256];
  const int i = (int)blockIdx.x * 256 + (int)threadIdx.x;
  red[threadIdx.x] = (i < n) ? deg[i] : 0;
  __syncthreads();
  for (int s = 128; s > 0; s >>= 1) {
    if ((int)threadIdx.x < s) red[threadIdx.x] += red[threadIdx.x + s];
    __syncthreads();
  }
  if (threadIdx.x == 0) bsum[blockIdx.x] = red[0];
}

__global__ __launch_bounds__(256) void scan_base_kernel(
    const int* __restrict__ bsum, int* __restrict__ bbase, int nb) {
  __shared__ int sh[256];
  const int t = threadIdx.x;
  const int x = (t < nb) ? bsum[t] : 0;
  sh[t] = x;
  __syncthreads();
  for (int d = 1; d < 256; d <<= 1) {
    const int v = (t >= d) ? sh[t - d] : 0;
    __syncthreads();
    sh[t] += v;
    __syncthreads();
  }
  if (t < nb) bbase[t] = sh[t] - x;  // exclusive
}

__global__ __launch_bounds__(256) void scan_write_kernel(
    const int* __restrict__ deg, const int* __restrict__ bbase,
    int* __restrict__ off, int* __restrict__ cursor, int n) {
  const int i = (int)blockIdx.x * 256 + (int)threadIdx.x;
  const int lane = threadIdx.x & 63;
  const int w = threadIdx.x >> 6;
  const int x = (i < n) ? deg[i] : 0;
  int inc = x;
#pragma unroll
  for (int d = 1; d < 64; d <<= 1) {
    const int t = __shfl_up(inc, d, 64);
    if (lane >= d) inc += t;
  }
  __shared__ int wsum[4];
  if (lane == 63) wsum[w] = inc;
  __syncthreads();
  int wb = 0;
#pragma unroll
  for (int k = 0; k < 4; ++k) wb += (k < w) ? wsum[k] : 0;
  const int excl = bbase[blockIdx.x] + wb + inc - x;
  if (i < n) {
    off[i] = excl;
    if (cursor) cursor[i] = excl;
    if (i == n - 1) off[n] = excl + x;
  }
}

// Fallback scatters (atomic cursor).
__global__ __launch_bounds__(256) void scatter_pay_kernel(
    const int* __restrict__ dst, const int* __restrict__ src,
    const float* __restrict__ vals, int* __restrict__ cursor,
    int2* __restrict__ pay, int E) {
  const int e = (int)blockIdx.x * 256 + (int)threadIdx.x;
  if (e < E) {
    const int pos = atomicAdd(&cursor[dst[e]], 1);
    pay[pos] = make_int2(src[e], __float_as_int(vals[e]));
  }
}

__global__ __launch_bounds__(256) void scatter_perm_kernel(
    const int* __restrict__ dst, int* __restrict__ cursor,
    int* __restrict__ perm, int E) {
  const int e = (int)blockIdx.x * 256 + (int)threadIdx.x;
  if (e < E) {
    const int pos = atomicAdd(&cursor[dst[e]], 1);
    perm[pos] = e;
  }
}

// ---------------------------------------------------------------------------
// Gather: one 64-lane wave per node; lane-parallel metadata, shfl broadcast,
// 8 independent H-row loads in flight. No fp32 atomics.
// ---------------------------------------------------------------------------
__device__ __forceinline__ float2 h_row2(const float* __restrict__ H, int s,
                                         int lane) {
  return reinterpret_cast<const float2*>(H + (size_t)s * OUT_F)[lane];
}

template <bool PAYLOAD>
__device__ __forceinline__ void gather_body(
    const float* __restrict__ H, const int2* __restrict__ pay,
    const float* __restrict__ vals, const int* __restrict__ src,
    const int* __restrict__ perm, const int* __restrict__ off,
    float* __restrict__ out, int wave, int lane) {
  const int b = off[wave];
  const int e = off[wave + 1];
  float accx = 0.f, accy = 0.f;

  for (int base = b; base < e; base += 64) {
    const int n = min(64, e - base);
    int s = 0;
    float v = 0.f;
    if (lane < n) {
      if (PAYLOAD) {
        const int2 p = pay[base + lane];
        s = p.x;
        v = __int_as_float(p.y);
      } else {
        const int id = perm[base + lane];
        v = vals[id];
        s = src[id];
      }
    }
    int k = 0;
    for (; k + 8 <= n; k += 8) {
      const int s0 = __shfl(s, k + 0, 64);
      const int s1 = __shfl(s, k + 1, 64);
      const int s2 = __shfl(s, k + 2, 64);
      const int s3 = __shfl(s, k + 3, 64);
      const int s4 = __shfl(s, k + 4, 64);
      const int s5 = __shfl(s, k + 5, 64);
      const int s6 = __shfl(s, k + 6, 64);
      const int s7 = __shfl(s, k + 7, 64);
      const float2 h0 = h_row2(H, s0, lane);
      const float2 h1 = h_row2(H, s1, lane);
      const float2 h2 = h_row2(H, s2, lane);
      const float2 h3 = h_row2(H, s3, lane);
      const float2 h4 = h_row2(H, s4, lane);
      const float2 h5 = h_row2(H, s5, lane);
      const float2 h6 = h_row2(H, s6, lane);
      const float2 h7 = h_row2(H, s7, lane);
      const float v0 = __shfl(v, k + 0, 64);
      const float v1 = __shfl(v, k + 1, 64);
      const float v2 = __shfl(v, k + 2, 64);
      const float v3 = __shfl(v, k + 3, 64);
      const float v4 = __shfl(v, k + 4, 64);
      const float v5 = __shfl(v, k + 5, 64);
      const float v6 = __shfl(v, k + 6, 64);
      const float v7 = __shfl(v, k + 7, 64);
      accx = fmaf(v0, h0.x, accx); accy = fmaf(v0, h0.y, accy);
      accx = fmaf(v1, h1.x, accx); accy = fmaf(v1, h1.y, accy);
      accx = fmaf(v2, h2.x, accx); accy = fmaf(v2, h2.y, accy);
      accx = fmaf(v3, h3.x, accx); accy = fmaf(v3, h3.y, accy);
      accx = fmaf(v4, h4.x, accx); accy = fmaf(v4, h4.y, accy);
      accx = fmaf(v5, h5.x, accx); accy = fmaf(v5, h5.y, accy);
      accx = fmaf(v6, h6.x, accx); accy = fmaf(v6, h6.y, accy);
      accx = fmaf(v7, h7.x, accx); accy = fmaf(v7, h7.y, accy);
    }
    for (; k < n; ++k) {
      const int sk = __shfl(s, k, 64);
      const float vk = __shfl(v, k, 64);
      const float2 hv = h_row2(H, sk, lane);
      accx = fmaf(vk, hv.x, accx);
      accy = fmaf(vk, hv.y, accy);
    }
  }
  float2 o;
  o.x = accx;
  o.y = accy;
  reinterpret_cast<float2*>(out + (size_t)wave * OUT_F)[lane] = o;
}

__global__ __launch_bounds__(256) void gather_pay_kernel(
    const float* __restrict__ H, const int2* __restrict__ pay,
    const int* __restrict__ off, float* __restrict__ out, int M) {
  const int wave = (int)((blockIdx.x * blockDim.x + threadIdx.x) >> 6);
  const int lane = threadIdx.x & 63;
  if (wave >= M) return;
  gather_body<true>(H, pay, nullptr, nullptr, nullptr, off, out, wave, lane);
}

__global__ __launch_bounds__(256) void gather_perm_kernel(
    const float* __restrict__ H, const float* __restrict__ vals,
    const int* __restrict__ src, const int* __restrict__ off,
    const int* __restrict__ perm, float* __restrict__ out, int M) {
  const int wave = (int)((blockIdx.x * blockDim.x + threadIdx.x) >> 6);
  const int lane = threadIdx.x & 63;
  if (wave >= M) return;
  gather_body<false>(H, nullptr, vals, src, perm, off, out, wave, lane);
}

// ---------------------------------------------------------------------------
extern "C" void kernel_launch(void* const* d_in, const int* in_sizes, int n_in,
                              void* d_out, int out_size, void* d_ws,
                              size_t ws_size, hipStream_t stream) {
  const float* X = (const float*)d_in[0];        // [M, 256]
  const float* W = (const float*)d_in[1];        // [256, 128]
  const float* bias = (const float*)d_in[2];     // [128]
  const float* adj_vals = (const float*)d_in[3]; // [E]
  const int* edge_src = (const int*)d_in[4];     // [E]
  const int* edge_dst = (const int*)d_in[5];     // [E]
  float* out = (float*)d_out;                    // [M, 128]

  const int M = in_sizes[0] / IN_F;  // 50000
  const int E = in_sizes[3];         // 800000

  char* ws = (char*)d_ws;
  size_t o = 0;
  auto take = [&](size_t bytes) {
    void* p = ws + o;
    o = (o + bytes + 15) & ~(size_t)15;
    return p;
  };
  float* H = (float*)take((size_t)M * OUT_F * sizeof(float));  // 25.6 MB
  int* off = (int*)take((size_t)(M + 1) * sizeof(int));
  int* deg = (int*)take((size_t)M * sizeof(int));
  const int nb = (M + 255) / 256;  // 196 (<= 256)
  const size_t scanb = 2 * (((size_t)nb * sizeof(int) + 15) & ~(size_t)15);

  // Tier select by ws budget (deterministic).
  const size_t base = o;
  const size_t need_primary = base + ((size_t)E + M) * sizeof(int) +
                              (size_t)E * sizeof(int2) + scanb + 64;
  const size_t need_fb1 =
      base + (size_t)M * sizeof(int) + (size_t)E * sizeof(int2) + scanb + 64;
  const int tier = (ws_size == 0 || need_primary <= ws_size) ? 0
                   : (need_fb1 <= ws_size)                   ? 1
                                                             : 2;

  int *tmp = nullptr, *cursor = nullptr, *perm = nullptr;
  int2* pay = nullptr;
  if (tier == 0) {
    tmp = (int*)take((size_t)E * sizeof(int));
    pay = (int2*)take((size_t)E * sizeof(int2));
  } else if (tier == 1) {
    cursor = (int*)take((size_t)M * sizeof(int));
    pay = (int2*)take((size_t)E * sizeof(int2));
  } else {
    cursor = (int*)take((size_t)M * sizeof(int));
    perm = (int*)take((size_t)E * sizeof(int));
  }
  int* bsum = (int*)take((size_t)nb * sizeof(int));
  int* bbase = (int*)take((size_t)nb * sizeof(int));

  hipMemsetAsync(deg, 0, (size_t)M * sizeof(int), stream);

  const int gemmBlocks = (M + BM - 1) / BM;  // 782
  const int eb = (E + 255) / 256;
  dim3 gather_grid((M + 3) / 4);  // 4 waves (256 threads) per block

  if (tier == 0) {
    // 1. histogram (grid-stride) -> deg, tmp
    hist_kernel<<<1024, 256, 0, stream>>>(edge_dst, deg, tmp, E);
    // 2. single-block scan -> off
    scan_kernel<<<1, 1024, 0, stream>>>(deg, off, M);
    // 3. GEMM (round-9 structure) fused with atomic-free placement
    const int placeBlocks = 1024;
    gemm_place_kernel<<<gemmBlocks + placeBlocks, 256, 0, stream>>>(
        X, W, bias, H, M, edge_dst, edge_src, adj_vals, off, tmp, pay, E,
        gemmBlocks, placeBlocks);
    // 4. gather
    gather_pay_kernel<<<gather_grid, 256, 0, stream>>>(H, pay, off, out, M);
  } else {
    // Fallback: hist (no tmp), 3-kernel scan w/ cursor, GEMM alone, scatter.
    hist_kernel<<<1024, 256, 0, stream>>>(edge_dst, deg, nullptr, E);
    scan_partial_kernel<<<nb, 256, 0, stream>>>(deg, bsum, M);
    scan_base_kernel<<<1, 256, 0, stream>>>(bsum, bbase, nb);
    scan_write_kernel<<<nb, 256, 0, stream>>>(deg, bbase, off, cursor, M);
    gemm_place_kernel<<<gemmBlocks, 256, 0, stream>>>(
        X, W, bias, H, M, nullptr, nullptr, nullptr, nullptr, nullptr, nullptr,
        0, gemmBlocks, 0);
    if (tier == 1) {
      scatter_pay_kernel<<<eb, 256, 0, stream>>>(edge_dst, edge_src, adj_vals,
                                                 cursor, pay, E);
      gather_pay_kernel<<<gather_grid, 256, 0, stream>>>(H, pay, off, out, M);
    } else {
      scatter_perm_kernel<<<eb, 256, 0, stream>>>(edge_dst, cursor, perm, E);
      gather_perm_kernel<<<gather_grid, 256, 0, stream>>>(H, adj_vals, edge_src,
                                                          off, perm, out, M);
    }
  }
}

// Round 13
// 139.286 us; speedup vs baseline: 1.6562x; 1.6562x over previous
//
#include <hip/hip_runtime.h>

static constexpr int IN_F = 256;
static constexpr int OUT_F = 128;
static constexpr int BM = 64, BN = 128, BK = 32;
static constexpr int NT = IN_F / BK;  // 8 K-tiles

// ---------------------------------------------------------------------------
// Fused kernel (round-9 proven, 71.5 us). Blocks [0, gemmBlocks): H = X*W +
// bias; BM=64, BK=32, 4x8 micro-tile, 256 threads, single LDS buffer +
// register prefetch. Blocks >= gemmBlocks: edge-dst histogram + within-node
// slot into tmp[e] (atomics hidden under GEMM).
// ---------------------------------------------------------------------------
__global__ __launch_bounds__(256) void gemm_hist_kernel(
    const float* __restrict__ X, const float* __restrict__ W,
    const float* __restrict__ bias, float* __restrict__ H, int M,
    const int* __restrict__ dst, int* __restrict__ deg,
    int* __restrict__ tmp, int E, int gemmBlocks) {
  if ((int)blockIdx.x >= gemmBlocks) {
    const int e = ((int)blockIdx.x - gemmBlocks) * 256 + (int)threadIdx.x;
    if (e < E) {
      const int s = atomicAdd(&deg[dst[e]], 1);
      if (tmp) tmp[e] = s;
    }
    return;
  }

  __shared__ float As[BK][BM + 4];  // 32 x 68 x 4B = 8704 B
  __shared__ float Bs[BK][BN];      // 32 x 128 x 4B = 16384 B

  const int tid = threadIdx.x;
  const int tx = tid & 15;   // cols tx*4..+3 and 64+tx*4..+3
  const int ty = tid >> 4;   // rows ty*4..+3
  const int row0 = (int)blockIdx.x * BM;

  const int ar = tid >> 3;          // 0..31 (+32)
  const int ac4 = (tid & 7) << 2;   // 0,4,..,28
  const int bk_ = tid >> 5;         // 0..7
  const int bn4 = (tid & 31) << 2;  // 0..124

  float acc[4][8];
#pragma unroll
  for (int i = 0; i < 4; ++i)
#pragma unroll
    for (int j = 0; j < 8; ++j) acc[i][j] = 0.f;

  const float4 fz = make_float4(0.f, 0.f, 0.f, 0.f);
  const int gr0 = row0 + ar;
  const int gr1 = row0 + ar + 32;

  // Prologue: tile 0 -> registers.
  float4 cA0 = (gr0 < M) ? *(const float4*)(X + (size_t)gr0 * IN_F + ac4) : fz;
  float4 cA1 = (gr1 < M) ? *(const float4*)(X + (size_t)gr1 * IN_F + ac4) : fz;
  float4 cB0 = *(const float4*)(W + (size_t)(bk_ + 0) * OUT_F + bn4);
  float4 cB1 = *(const float4*)(W + (size_t)(bk_ + 8) * OUT_F + bn4);
  float4 cB2 = *(const float4*)(W + (size_t)(bk_ + 16) * OUT_F + bn4);
  float4 cB3 = *(const float4*)(W + (size_t)(bk_ + 24) * OUT_F + bn4);

#pragma unroll 1
  for (int t = 0; t < NT; ++t) {
    // Stage current tile regs -> LDS.
    As[ac4 + 0][ar] = cA0.x; As[ac4 + 1][ar] = cA0.y;
    As[ac4 + 2][ar] = cA0.z; As[ac4 + 3][ar] = cA0.w;
    As[ac4 + 0][ar + 32] = cA1.x; As[ac4 + 1][ar + 32] = cA1.y;
    As[ac4 + 2][ar + 32] = cA1.z; As[ac4 + 3][ar + 32] = cA1.w;
    *(float4*)&Bs[bk_ + 0][bn4] = cB0;
    *(float4*)&Bs[bk_ + 8][bn4] = cB1;
    *(float4*)&Bs[bk_ + 16][bn4] = cB2;
    *(float4*)&Bs[bk_ + 24][bn4] = cB3;
    __syncthreads();

    // Prefetch next tile (in flight through the compute phase).
    if (t + 1 < NT) {
      const int k0 = (t + 1) * BK;
      cA0 = (gr0 < M) ? *(const float4*)(X + (size_t)gr0 * IN_F + k0 + ac4) : fz;
      cA1 = (gr1 < M) ? *(const float4*)(X + (size_t)gr1 * IN_F + k0 + ac4) : fz;
      cB0 = *(const float4*)(W + (size_t)(k0 + bk_ + 0) * OUT_F + bn4);
      cB1 = *(const float4*)(W + (size_t)(k0 + bk_ + 8) * OUT_F + bn4);
      cB2 = *(const float4*)(W + (size_t)(k0 + bk_ + 16) * OUT_F + bn4);
      cB3 = *(const float4*)(W + (size_t)(k0 + bk_ + 24) * OUT_F + bn4);
    }

#pragma unroll
    for (int kk = 0; kk < BK; ++kk) {
      const float4 a = *(const float4*)&As[kk][ty * 4];
      const float4 b0 = *(const float4*)&Bs[kk][tx * 4];
      const float4 b1 = *(const float4*)&Bs[kk][64 + tx * 4];
      const float av[4] = {a.x, a.y, a.z, a.w};
#pragma unroll
      for (int i = 0; i < 4; ++i) {
        acc[i][0] = fmaf(av[i], b0.x, acc[i][0]);
        acc[i][1] = fmaf(av[i], b0.y, acc[i][1]);
        acc[i][2] = fmaf(av[i], b0.z, acc[i][2]);
        acc[i][3] = fmaf(av[i], b0.w, acc[i][3]);
        acc[i][4] = fmaf(av[i], b1.x, acc[i][4]);
        acc[i][5] = fmaf(av[i], b1.y, acc[i][5]);
        acc[i][6] = fmaf(av[i], b1.z, acc[i][6]);
        acc[i][7] = fmaf(av[i], b1.w, acc[i][7]);
      }
    }
    __syncthreads();
  }

  float bv0[4], bv1[4];
#pragma unroll
  for (int j = 0; j < 4; ++j) {
    bv0[j] = bias[tx * 4 + j];
    bv1[j] = bias[64 + tx * 4 + j];
  }
#pragma unroll
  for (int i = 0; i < 4; ++i) {
    const int gr = row0 + ty * 4 + i;
    if (gr < M) {
      float4 o0, o1;
      o0.x = acc[i][0] + bv0[0]; o0.y = acc[i][1] + bv0[1];
      o0.z = acc[i][2] + bv0[2]; o0.w = acc[i][3] + bv0[3];
      o1.x = acc[i][4] + bv1[0]; o1.y = acc[i][5] + bv1[1];
      o1.z = acc[i][6] + bv1[2]; o1.w = acc[i][7] + bv1[3];
      *(float4*)(H + (size_t)gr * OUT_F + tx * 4) = o0;
      *(float4*)(H + (size_t)gr * OUT_F + 64 + tx * 4) = o1;
    }
  }
}

// ---------------------------------------------------------------------------
// Hierarchical exclusive scan of deg[n] -> off[n+1]; optional cursor=off copy.
// ---------------------------------------------------------------------------
__global__ __launch_bounds__(256) void scan_partial_kernel(
    const int* __restrict__ deg, int* __restrict__ bsum, int n) {
  __shared__ int red[256];
  const int i = (int)blockIdx.x * 256 + (int)threadIdx.x;
  red[threadIdx.x] = (i < n) ? deg[i] : 0;
  __syncthreads();
  for (int s = 128; s > 0; s >>= 1) {
    if ((int)threadIdx.x < s) red[threadIdx.x] += red[threadIdx.x + s];
    __syncthreads();
  }
  if (threadIdx.x == 0) bsum[blockIdx.x] = red[0];
}

__global__ __launch_bounds__(256) void scan_base_kernel(
    const int* __restrict__ bsum, int* __restrict__ bbase, int nb) {
  __shared__ int sh[256];
  const int t = threadIdx.x;
  const int x = (t < nb) ? bsum[t] : 0;
  sh[t] = x;
  __syncthreads();
  for (int d = 1; d < 256; d <<= 1) {
    const int v = (t >= d) ? sh[t - d] : 0;
    __syncthreads();
    sh[t] += v;
    __syncthreads();
  }
  if (t < nb) bbase[t] = sh[t] - x;  // exclusive
}

__global__ __launch_bounds__(256) void scan_write_kernel(
    const int* __restrict__ deg, const int* __restrict__ bbase,
    int* __restrict__ off, int* __restrict__ cursor, int n) {
  const int i = (int)blockIdx.x * 256 + (int)threadIdx.x;
  const int lane = threadIdx.x & 63;
  const int w = threadIdx.x >> 6;
  const int x = (i < n) ? deg[i] : 0;
  int inc = x;
#pragma unroll
  for (int d = 1; d < 64; d <<= 1) {
    const int t = __shfl_up(inc, d, 64);
    if (lane >= d) inc += t;
  }
  __shared__ int wsum[4];
  if (lane == 63) wsum[w] = inc;
  __syncthreads();
  int wb = 0;
#pragma unroll
  for (int k = 0; k < 4; ++k) wb += (k < w) ? wsum[k] : 0;
  const int excl = bbase[blockIdx.x] + wb + inc - x;
  if (i < n) {
    off[i] = excl;
    if (cursor) cursor[i] = excl;
    if (i == n - 1) off[n] = excl + x;
  }
}

// ---------------------------------------------------------------------------
// Placement (primary, NO atomics): pos = off[dst[e]] + tmp[e].
// ---------------------------------------------------------------------------
__global__ __launch_bounds__(256) void place_kernel(
    const int* __restrict__ dst, const int* __restrict__ src,
    const float* __restrict__ vals, const int* __restrict__ off,
    const int* __restrict__ tmp, int2* __restrict__ pay, int E) {
  const int e = (int)blockIdx.x * 256 + (int)threadIdx.x;
  if (e < E) {
    const int pos = off[dst[e]] + tmp[e];
    pay[pos] = make_int2(src[e], __float_as_int(vals[e]));
  }
}

// Fallback scatters (atomic cursor).
__global__ __launch_bounds__(256) void scatter_pay_kernel(
    const int* __restrict__ dst, const int* __restrict__ src,
    const float* __restrict__ vals, int* __restrict__ cursor,
    int2* __restrict__ pay, int E) {
  const int e = (int)blockIdx.x * 256 + (int)threadIdx.x;
  if (e < E) {
    const int pos = atomicAdd(&cursor[dst[e]], 1);
    pay[pos] = make_int2(src[e], __float_as_int(vals[e]));
  }
}

__global__ __launch_bounds__(256) void scatter_perm_kernel(
    const int* __restrict__ dst, int* __restrict__ cursor,
    int* __restrict__ perm, int E) {
  const int e = (int)blockIdx.x * 256 + (int)threadIdx.x;
  if (e < E) {
    const int pos = atomicAdd(&cursor[dst[e]], 1);
    perm[pos] = e;
  }
}

// ---------------------------------------------------------------------------
// Gather: one 64-lane wave per node; lane-parallel metadata, shfl broadcast,
// 16 independent H-row loads in flight (was 8). Arrays indexed only by
// unrolled (compile-time) induction vars -> stay in registers.
// ---------------------------------------------------------------------------
__device__ __forceinline__ float2 h_row2(const float* __restrict__ H, int s,
                                         int lane) {
  return reinterpret_cast<const float2*>(H + (size_t)s * OUT_F)[lane];
}

template <bool PAYLOAD>
__device__ __forceinline__ void gather_body(
    const float* __restrict__ H, const int2* __restrict__ pay,
    const float* __restrict__ vals, const int* __restrict__ src,
    const int* __restrict__ perm, const int* __restrict__ off,
    float* __restrict__ out, int wave, int lane) {
  const int b = off[wave];
  const int e = off[wave + 1];
  float accx = 0.f, accy = 0.f;

  for (int base = b; base < e; base += 64) {
    const int n = min(64, e - base);
    int s = 0;
    float v = 0.f;
    if (lane < n) {
      if (PAYLOAD) {
        const int2 p = pay[base + lane];
        s = p.x;
        v = __int_as_float(p.y);
      } else {
        const int id = perm[base + lane];
        v = vals[id];
        s = src[id];
      }
    }
    int k = 0;
    // 16 independent row loads in flight.
    for (; k + 16 <= n; k += 16) {
      int sj[16];
      float2 hj[16];
      float vj[16];
#pragma unroll
      for (int j = 0; j < 16; ++j) sj[j] = __shfl(s, k + j, 64);
#pragma unroll
      for (int j = 0; j < 16; ++j) hj[j] = h_row2(H, sj[j], lane);
#pragma unroll
      for (int j = 0; j < 16; ++j) vj[j] = __shfl(v, k + j, 64);
#pragma unroll
      for (int j = 0; j < 16; ++j) {
        accx = fmaf(vj[j], hj[j].x, accx);
        accy = fmaf(vj[j], hj[j].y, accy);
      }
    }
    for (; k + 8 <= n; k += 8) {
      int sj[8];
      float2 hj[8];
      float vj[8];
#pragma unroll
      for (int j = 0; j < 8; ++j) sj[j] = __shfl(s, k + j, 64);
#pragma unroll
      for (int j = 0; j < 8; ++j) hj[j] = h_row2(H, sj[j], lane);
#pragma unroll
      for (int j = 0; j < 8; ++j) vj[j] = __shfl(v, k + j, 64);
#pragma unroll
      for (int j = 0; j < 8; ++j) {
        accx = fmaf(vj[j], hj[j].x, accx);
        accy = fmaf(vj[j], hj[j].y, accy);
      }
    }
    for (; k < n; ++k) {
      const int sk = __shfl(s, k, 64);
      const float vk = __shfl(v, k, 64);
      const float2 hv = h_row2(H, sk, lane);
      accx = fmaf(vk, hv.x, accx);
      accy = fmaf(vk, hv.y, accy);
    }
  }
  float2 o;
  o.x = accx;
  o.y = accy;
  reinterpret_cast<float2*>(out + (size_t)wave * OUT_F)[lane] = o;
}

__global__ __launch_bounds__(256) void gather_pay_kernel(
    const float* __restrict__ H, const int2* __restrict__ pay,
    const int* __restrict__ off, float* __restrict__ out, int M) {
  const int wave = (int)((blockIdx.x * blockDim.x + threadIdx.x) >> 6);
  const int lane = threadIdx.x & 63;
  if (wave >= M) return;
  gather_body<true>(H, pay, nullptr, nullptr, nullptr, off, out, wave, lane);
}

__global__ __launch_bounds__(256) void gather_perm_kernel(
    const float* __restrict__ H, const float* __restrict__ vals,
    const int* __restrict__ src, const int* __restrict__ off,
    const int* __restrict__ perm, float* __restrict__ out, int M) {
  const int wave = (int)((blockIdx.x * blockDim.x + threadIdx.x) >> 6);
  const int lane = threadIdx.x & 63;
  if (wave >= M) return;
  gather_body<false>(H, nullptr, vals, src, perm, off, out, wave, lane);
}

// ---------------------------------------------------------------------------
extern "C" void kernel_launch(void* const* d_in, const int* in_sizes, int n_in,
                              void* d_out, int out_size, void* d_ws,
                              size_t ws_size, hipStream_t stream) {
  const float* X = (const float*)d_in[0];        // [M, 256]
  const float* W = (const float*)d_in[1];        // [256, 128]
  const float* bias = (const float*)d_in[2];     // [128]
  const float* adj_vals = (const float*)d_in[3]; // [E]
  const int* edge_src = (const int*)d_in[4];     // [E]
  const int* edge_dst = (const int*)d_in[5];     // [E]
  float* out = (float*)d_out;                    // [M, 128]

  const int M = in_sizes[0] / IN_F;  // 50000
  const int E = in_sizes[3];         // 800000

  char* ws = (char*)d_ws;
  size_t o = 0;
  auto take = [&](size_t bytes) {
    void* p = ws + o;
    o = (o + bytes + 15) & ~(size_t)15;
    return p;
  };
  float* H = (float*)take((size_t)M * OUT_F * sizeof(float));  // 25.6 MB
  int* off = (int*)take((size_t)(M + 1) * sizeof(int));
  int* deg = (int*)take((size_t)M * sizeof(int));
  const int nb = (M + 255) / 256;  // 196 (<= 256)
  const size_t scanb = 2 * (((size_t)nb * sizeof(int) + 15) & ~(size_t)15);

  // Tier select by ws budget (deterministic).
  const size_t base = o;
  const size_t need_primary = base + ((size_t)E + M) * sizeof(int) +
                              (size_t)E * sizeof(int2) + scanb + 64;
  const size_t need_fb1 =
      base + (size_t)M * sizeof(int) + (size_t)E * sizeof(int2) + scanb + 64;
  const int tier = (ws_size == 0 || need_primary <= ws_size) ? 0
                   : (need_fb1 <= ws_size)                   ? 1
                                                             : 2;

  int *tmp = nullptr, *cursor = nullptr, *perm = nullptr;
  int2* pay = nullptr;
  if (tier == 0) {
    tmp = (int*)take((size_t)E * sizeof(int));
    pay = (int2*)take((size_t)E * sizeof(int2));
  } else if (tier == 1) {
    cursor = (int*)take((size_t)M * sizeof(int));
    pay = (int2*)take((size_t)E * sizeof(int2));
  } else {
    cursor = (int*)take((size_t)M * sizeof(int));
    perm = (int*)take((size_t)E * sizeof(int));
  }
  int* bsum = (int*)take((size_t)nb * sizeof(int));
  int* bbase = (int*)take((size_t)nb * sizeof(int));

  hipMemsetAsync(deg, 0, (size_t)M * sizeof(int), stream);

  const int gemmBlocks = (M + BM - 1) / BM;  // 782
  const int histBlocks = (E + 255) / 256;    // 3125
  gemm_hist_kernel<<<gemmBlocks + histBlocks, 256, 0, stream>>>(
      X, W, bias, H, M, edge_dst, deg, tmp, E, gemmBlocks);

  scan_partial_kernel<<<nb, 256, 0, stream>>>(deg, bsum, M);
  scan_base_kernel<<<1, 256, 0, stream>>>(bsum, bbase, nb);
  scan_write_kernel<<<nb, 256, 0, stream>>>(deg, bbase, off, cursor, M);

  const int eb = (E + 255) / 256;
  dim3 gather_grid((M + 3) / 4);  // 4 waves (256 threads) per block
  if (tier == 0) {
    place_kernel<<<eb, 256, 0, stream>>>(edge_dst, edge_src, adj_vals, off,
                                         tmp, pay, E);
    gather_pay_kernel<<<gather_grid, 256, 0, stream>>>(H, pay, off, out, M);
  } else if (tier == 1) {
    scatter_pay_kernel<<<eb, 256, 0, stream>>>(edge_dst, edge_src, adj_vals,
                                               cursor, pay, E);
    gather_pay_kernel<<<gather_grid, 256, 0, stream>>>(H, pay, off, out, M);
  } else {
    scatter_perm_kernel<<<eb, 256, 0, stream>>>(edge_dst, cursor, perm, E);
    gather_perm_kernel<<<gather_grid, 256, 0, stream>>>(H, adj_vals, edge_src,
                                                        off, perm, out, M);
  }
}